// Round 1
// 407.046 us; speedup vs baseline: 1.0064x; 1.0064x over previous
//
#include <hip/hip_runtime.h>
#include <hip/hip_bf16.h>
#include <math.h>

#define N_NODES 100000
#define N_EDGES 1600000
#define F_IN 256
#define DIM 32
#define NC 40

#define NBLK 391            // ceil(100000/256)

// fill partitioning: 4 partitions (dst read 4x instead of 8x)
#define NPART 4
#define FPART_SZ 25000      // N_NODES / NPART

typedef _Float16 half_t;
typedef _Float16 h8 __attribute__((ext_vector_type(8)));
typedef float f32x4 __attribute__((ext_vector_type(4)));
union H8 { float4 f4; half_t h[8]; };

// ================= degree =================
__global__ void deg_kernel(const int* __restrict__ dst, int* __restrict__ degi) {
    int i = blockIdx.x * blockDim.x + threadIdx.x;
    if (i < N_EDGES) atomicAdd(&degi[dst[i]], 1);
}

// ================= deterministic prefix scan (3 phases) =================
__device__ __forceinline__ int block_scan_excl(int v, int& tot) {
    int lane = threadIdx.x & 63;
    int wid = threadIdx.x >> 6;
    int s = v;
#pragma unroll
    for (int off = 1; off < 64; off <<= 1) {
        int t = __shfl_up(s, off, 64);
        if (lane >= off) s += t;
    }
    __shared__ int wsum[8];
    if (lane == 63) wsum[wid] = s;
    __syncthreads();
    int nw = (blockDim.x + 63) >> 6;
    int wprev = 0, total = 0;
    for (int i = 0; i < nw; ++i) {
        int t = wsum[i];
        if (i < wid) wprev += t;
        total += t;
    }
    tot = total;
    return wprev + s - v;   // exclusive prefix
}

__global__ void scanA_kernel(const int* __restrict__ degi, int* __restrict__ partial) {
    int i = blockIdx.x * 256 + threadIdx.x;
    int v = (i < N_NODES) ? degi[i] : 0;
    int tot;
    block_scan_excl(v, tot);
    if (threadIdx.x == 0) partial[blockIdx.x] = tot;
}

__global__ void scanB_kernel(int* __restrict__ partial, int* __restrict__ blockoff) {
    int i = threadIdx.x;   // 512 threads
    int v = (i < NBLK) ? partial[i] : 0;
    int tot;
    int ex = block_scan_excl(v, tot);
    if (i < NBLK) blockoff[i] = ex;
}

__global__ void scanC_kernel(const int* __restrict__ degi,
                             const int* __restrict__ blockoff,
                             int* __restrict__ rowstart,
                             int* __restrict__ cursor) {
    int i = blockIdx.x * 256 + threadIdx.x;
    int v = (i < N_NODES) ? degi[i] : 0;
    int tot;
    int ex = block_scan_excl(v, tot) + blockoff[blockIdx.x];
    if (i < N_NODES) {
        rowstart[i] = ex;
        cursor[i] = ex;
    }
}

// ================= partitioned fill (single pass, 4 partitions) =================
__global__ __launch_bounds__(256)
void fill_xcd_kernel(const int* __restrict__ src,
                     const int* __restrict__ dst,
                     int* __restrict__ cursor,
                     int* __restrict__ csr) {
    int x = blockIdx.x & (NPART - 1);             // partition id
    int gblk = blockIdx.x >> 2;                   // block index within group
    int gsize = gridDim.x >> 2;                   // blocks per group
    int tid = gblk * blockDim.x + threadIdx.x;    // thread id within group
    int stride = gsize * blockDim.x;
    int lo = x * FPART_SZ;
    int hi = lo + FPART_SZ;

    const int4* dst4 = (const int4*)dst;
    for (int e4 = tid; e4 < N_EDGES / 4; e4 += stride) {
        int4 d4 = dst4[e4];
        int e = e4 * 4;
#pragma unroll
        for (int c = 0; c < 4; ++c) {
            int d = (c == 0) ? d4.x : (c == 1) ? d4.y : (c == 2) ? d4.z : d4.w;
            if (d >= lo && d < hi) {
                int pos = atomicAdd(&cursor[d], 1);
                csr[pos] = src[e + c];
            }
        }
    }
}

// ================= W1 transpose + fp16 convert (Wt[64][256]) =================
__global__ void wconv1(const float* __restrict__ W1l,
                       const float* __restrict__ W1r,
                       half_t* __restrict__ Wt) {
    int i = blockIdx.x * 256 + threadIdx.x;   // i = c*256 + k
    if (i >= 64 * F_IN) return;
    int c = i >> 8;
    int k = i & 255;
    float v = (c < DIM) ? W1l[(size_t)k * DIM + c] : W1r[(size_t)k * DIM + (c - DIM)];
    Wt[i] = (half_t)v;
}

// ================= layer-1 projection via MFMA (no LDS) =================
// Block = 256 threads = 4 waves; wave computes 16 nodes x 64 cols.
// A-frag (x, fp32->fp16 in reg) straight from global; B-frag from Wt (L2-resident).
// C/D layout (m89-verified): col = lane&15, row = (lane>>4)*4 + reg.
__global__ __launch_bounds__(256)
void proj1_mfma(const float* __restrict__ x,
                const half_t* __restrict__ Wt,
                half_t* __restrict__ P1h,
                half_t* __restrict__ R1h) {
    int wid = threadIdx.x >> 6;
    int lane = threadIdx.x & 63;
    int n0 = blockIdx.x * 64 + wid * 16;

    int arow = lane & 15;        // A row (node) for input frag
    int kb = lane >> 4;          // k sub-block 0..3 (8 elems each)
    int node = n0 + arow;
    int ldnode = node < N_NODES ? node : N_NODES - 1;
    const float* xrow = x + (size_t)ldnode * F_IN + kb * 8;
    const half_t* wb = Wt + (size_t)arow * F_IN + kb * 8;   // col = lane&15 for B frag

    f32x4 acc[4];
#pragma unroll
    for (int ct = 0; ct < 4; ++ct) acc[ct] = (f32x4){0.f, 0.f, 0.f, 0.f};

#pragma unroll
    for (int k0 = 0; k0 < F_IN; k0 += 32) {
        float4 a0 = *(const float4*)&xrow[k0];
        float4 a1 = *(const float4*)&xrow[k0 + 4];
        h8 af;
        af[0] = (half_t)a0.x; af[1] = (half_t)a0.y;
        af[2] = (half_t)a0.z; af[3] = (half_t)a0.w;
        af[4] = (half_t)a1.x; af[5] = (half_t)a1.y;
        af[6] = (half_t)a1.z; af[7] = (half_t)a1.w;
#pragma unroll
        for (int ct = 0; ct < 4; ++ct) {
            h8 bf = *(const h8*)&wb[(size_t)ct * 16 * F_IN + k0];
            acc[ct] = __builtin_amdgcn_mfma_f32_16x16x32_f16(af, bf, acc[ct], 0, 0, 0);
        }
    }

    int jrow = (lane >> 4) * 4;     // output row base within 16-node tile
    int cc = lane & 15;             // output col within 16-col tile
#pragma unroll
    for (int ct = 0; ct < 4; ++ct) {
        int cglob = ct * 16 + cc;
        half_t* outp = (cglob < DIM) ? (P1h + cglob) : (R1h + (cglob - DIM));
#pragma unroll
        for (int j = 0; j < 4; ++j) {
            int n = n0 + jrow + j;
            if (n < N_NODES) outp[(size_t)n * DIM] = (half_t)acc[ct][j];
        }
    }
}

// ================= gather engine =================
__device__ __forceinline__ void gather_node(const int* __restrict__ csr,
                                            const half_t* __restrict__ feat,
                                            int rs, int re, int q8, float acc[8]) {
#pragma unroll
    for (int i = 0; i < 8; ++i) acc[i] = 0.f;
    int e = rs;
    for (; e + 2 <= re; e += 2) {
        int s0 = csr[e];
        int s1 = csr[e + 1];
        H8 u0, u1;
        u0.f4 = *(const float4*)&feat[(size_t)s0 * DIM + q8];
        u1.f4 = *(const float4*)&feat[(size_t)s1 * DIM + q8];
#pragma unroll
        for (int i = 0; i < 8; ++i) acc[i] += (float)u0.h[i] + (float)u1.h[i];
    }
    if (e < re) {
        int s0 = csr[e];
        H8 u0;
        u0.f4 = *(const float4*)&feat[(size_t)s0 * DIM + q8];
#pragma unroll
        for (int i = 0; i < 8; ++i) acc[i] += (float)u0.h[i];
    }
}

// ================= layer-1 aggregate + relu (h in fp16) =================
__global__ __launch_bounds__(256)
void agg1_h_kernel(const int* __restrict__ rowstart,
                   const int* __restrict__ degi,
                   const int* __restrict__ csr,
                   const half_t* __restrict__ P1h,
                   const half_t* __restrict__ R1h,
                   const float* __restrict__ b1,
                   half_t* __restrict__ h) {
    int wave = blockIdx.x * 4 + (threadIdx.x >> 6);
    int lane = threadIdx.x & 63;
    int node = wave * 16 + (lane >> 2);
    if (node >= N_NODES) return;
    int q8 = (lane & 3) * 8;
    int rs = rowstart[node];
    int dg = degi[node];
    float acc[8];
    gather_node(csr, P1h, rs, rs + dg, q8, acc);
    float inv = 1.0f / (float)max(dg, 1);
    H8 r;
    r.f4 = *(const float4*)&R1h[(size_t)node * DIM + q8];
    float4 bb0 = *(const float4*)&b1[q8];
    float4 bb1 = *(const float4*)&b1[q8 + 4];
    float rb[8] = { (float)r.h[0] + bb0.x, (float)r.h[1] + bb0.y,
                    (float)r.h[2] + bb0.z, (float)r.h[3] + bb0.w,
                    (float)r.h[4] + bb1.x, (float)r.h[5] + bb1.y,
                    (float)r.h[6] + bb1.z, (float)r.h[7] + bb1.w };
    H8 o;
#pragma unroll
    for (int i = 0; i < 8; ++i) {
        float v = fmaf(acc[i], inv, rb[i]);
        o.h[i] = (half_t)(v > 0.f ? v : 0.f);
    }
    *(float4*)&h[(size_t)node * DIM + q8] = o.f4;
}

// ================= layer-2 aggregate (a2 in fp16, inv applied) =================
__global__ __launch_bounds__(256)
void agg2_kernel(const int* __restrict__ rowstart,
                 const int* __restrict__ degi,
                 const int* __restrict__ csr,
                 const half_t* __restrict__ h,
                 half_t* __restrict__ a2h) {
    int wave = blockIdx.x * 4 + (threadIdx.x >> 6);
    int lane = threadIdx.x & 63;
    int node = wave * 16 + (lane >> 2);
    if (node >= N_NODES) return;
    int q8 = (lane & 3) * 8;
    int rs = rowstart[node];
    int dg = degi[node];
    float acc[8];
    gather_node(csr, h, rs, rs + dg, q8, acc);
    float inv = 1.0f / (float)max(dg, 1);
    H8 o;
#pragma unroll
    for (int i = 0; i < 8; ++i) o.h[i] = (half_t)(acc[i] * inv);
    *(float4*)&a2h[(size_t)node * DIM + q8] = o.f4;
}

// ================= dense epilogue =================
__global__ __launch_bounds__(256)
void out_dense(const half_t* __restrict__ a2h,
               const half_t* __restrict__ h,
               const float* __restrict__ W2l,
               const float* __restrict__ W2r,
               const float* __restrict__ b2,
               float* __restrict__ out) {
    __shared__ float sWl[DIM * NC];
    __shared__ float sWr[DIM * NC];
    __shared__ float sb[NC];
    for (int i = threadIdx.x; i < DIM * NC; i += 256) {
        sWl[i] = W2l[i];
        sWr[i] = W2r[i];
    }
    if (threadIdx.x < NC) sb[threadIdx.x] = b2[threadIdx.x];
    __syncthreads();

    int n = blockIdx.x * 256 + threadIdx.x;
    if (n >= N_NODES) return;

    float av[32], hv[32];
#pragma unroll
    for (int c = 0; c < 4; ++c) {
        H8 ua, uh;
        ua.f4 = *(const float4*)&a2h[(size_t)n * DIM + c * 8];
        uh.f4 = *(const float4*)&h[(size_t)n * DIM + c * 8];
#pragma unroll
        for (int i = 0; i < 8; ++i) {
            av[c * 8 + i] = (float)ua.h[i];
            hv[c * 8 + i] = (float)uh.h[i];
        }
    }

    float acc[NC];
#pragma unroll
    for (int c = 0; c < NC; ++c) acc[c] = sb[c];
#pragma unroll
    for (int k = 0; k < DIM; ++k) {
        float a = av[k], hh = hv[k];
#pragma unroll
        for (int c = 0; c < NC; ++c)
            acc[c] = fmaf(a, sWl[k * NC + c], fmaf(hh, sWr[k * NC + c], acc[c]));
    }

    float m = acc[0];
#pragma unroll
    for (int c = 1; c < NC; ++c) m = fmaxf(m, acc[c]);
    float s = 0.f;
#pragma unroll
    for (int c = 0; c < NC; ++c) s += __expf(acc[c] - m);
    float lg = m + __logf(s);
    float* orow = out + (size_t)n * NC;
#pragma unroll
    for (int c4 = 0; c4 < NC / 4; ++c4) {
        float4 v = make_float4(acc[c4 * 4] - lg, acc[c4 * 4 + 1] - lg,
                               acc[c4 * 4 + 2] - lg, acc[c4 * 4 + 3] - lg);
        *(float4*)&orow[c4 * 4] = v;
    }
}

// ================= launch =================
extern "C" void kernel_launch(void* const* d_in, const int* in_sizes, int n_in,
                              void* d_out, int out_size, void* d_ws, size_t ws_size,
                              hipStream_t stream) {
    const float* x   = (const float*)d_in[0];
    const int*   ei  = (const int*)d_in[1];   // int32 [2, E]
    const float* W1l = (const float*)d_in[2];
    const float* W1r = (const float*)d_in[3];
    const float* b1  = (const float*)d_in[4];
    const float* W2l = (const float*)d_in[5];
    const float* W2r = (const float*)d_in[6];
    const float* b2  = (const float*)d_in[7];
    float* out = (float*)d_out;

    const int* src = ei;
    const int* dst = ei + N_EDGES;

    char* ws = (char*)d_ws;
    int*    degi     = (int*)ws;      ws += sizeof(int) * 102400;
    int*    rowstart = (int*)ws;      ws += sizeof(int) * 102400;
    int*    cursor   = (int*)ws;      ws += sizeof(int) * 102400;
    int*    partial  = (int*)ws;      ws += sizeof(int) * 512;
    int*    blockoff = (int*)ws;      ws += sizeof(int) * 512;
    int*    csr      = (int*)ws;      ws += sizeof(int) * N_EDGES;
    half_t* P1h      = (half_t*)ws;   ws += sizeof(half_t) * N_NODES * DIM;
    half_t* h        = (half_t*)ws;   ws += sizeof(half_t) * N_NODES * DIM;
    half_t* a2h      = (half_t*)ws;   ws += sizeof(half_t) * N_NODES * DIM;
    half_t* R1h      = (half_t*)ws;   ws += sizeof(half_t) * N_NODES * DIM;
    half_t* Wt       = (half_t*)ws;   ws += sizeof(half_t) * 64 * F_IN;

    hipMemsetAsync(degi, 0, sizeof(int) * 102400, stream);

    wconv1<<<64, 256, 0, stream>>>(W1l, W1r, Wt);
    deg_kernel<<<(N_EDGES + 255) / 256, 256, 0, stream>>>(dst, degi);
    scanA_kernel<<<NBLK, 256, 0, stream>>>(degi, partial);
    scanB_kernel<<<1, 512, 0, stream>>>(partial, blockoff);
    scanC_kernel<<<NBLK, 256, 0, stream>>>(degi, blockoff, rowstart, cursor);
    fill_xcd_kernel<<<2048, 256, 0, stream>>>(src, dst, cursor, csr);

    proj1_mfma<<<(N_NODES + 63) / 64, 256, 0, stream>>>(x, Wt, P1h, R1h);

    int gather_blocks = (N_NODES + 63) / 64;
    agg1_h_kernel<<<gather_blocks, 256, 0, stream>>>(rowstart, degi, csr, P1h, R1h, b1, h);
    agg2_kernel<<<gather_blocks, 256, 0, stream>>>(rowstart, degi, csr, h, a2h);
    out_dense<<<(N_NODES + 255) / 256, 256, 0, stream>>>(a2h, h, W2l, W2r, b2, out);
}